// Round 8
// baseline (75.138 us; speedup 1.0000x reference)
//
#include <hip/hip_runtime.h>
#include <hip/hip_bf16.h>

namespace {
constexpr int NB    = 64;
constexpr int V0d   = 40, V1d = 40, V2d = 200;
constexpr int VOL   = V0d * V1d * V2d;        // 320,000
constexpr int NC0   = 5, NC1 = 5, NC2 = 21;
constexpr int CELLS = NC0 * NC1 * NC2;        // 525
constexpr int M     = NB * CELLS;             // 33600
constexpr int C1MAX = 104, C2MAX = 120;
constexpr int KS    = 104 * C1MAX * C2MAX;    // 1,297,920 dense compact keys
constexpr int SEG   = 4096;
constexpr int NSEG  = (KS + SEG - 1) / SEG;   // 317
constexpr int KSP   = NSEG * SEG;             // 1,298,432 (padded)
constexpr int CHVOL = 1000;
constexpr int RPB   = 4;                      // ranks per k_out block
constexpr int NQ    = M / RPB;                // 8400 = 8 * 1050
}

// Round through bf16 (expected outputs are bf16-rounded float32 values).
__device__ __forceinline__ float bf16r(float v) {
    return __bfloat162float(__float2bfloat16(v));
}

__device__ __forceinline__ int enc(int c0, int c1, int c2) {
    return (c0 * C1MAX + c1) * C2MAX + c2;
}

__global__ void k_zero(int* __restrict__ P, int4* __restrict__ mask4,
                       int4* __restrict__ desc4) {
    int idx = blockIdx.x * blockDim.x + threadIdx.x;
    int stride = gridDim.x * blockDim.x;
    int4* p4 = reinterpret_cast<int4*>(P);
    const int n4 = KSP / 4;
    for (int i = idx; i < n4; i += stride) p4[i] = make_int4(0, 0, 0, 0);
    const int m4 = M * 8 / 16;          // mask[M] (u64)
    for (int i = idx; i < m4; i += stride) mask4[i] = make_int4(0, 0, 0, 0);
    const int d4 = M * 4 / 16;          // desc[M] (u32)
    for (int i = idx; i < d4; i += stride) desc4[i] = make_int4(-1, -1, -1, -1);
}

__global__ void k_mark(const int* __restrict__ loc, int* __restrict__ P) {
    int m = blockIdx.x * blockDim.x + threadIdx.x;
    if (m >= M) return;
    int b = m / CELLS, cell = m % CELLS;
    int i = cell / (NC1 * NC2), j = (cell / NC2) % NC1, k = cell % NC2;
    P[enc(loc[b * 3 + 0] / 10 + i, loc[b * 3 + 1] / 10 + j,
          loc[b * 3 + 2] / 10 + k)] = 1;
}

__global__ __launch_bounds__(256) void k_scan_blocks(int* __restrict__ P,
                                                     int* __restrict__ Bsums) {
    int bid = blockIdx.x, t = threadIdx.x;
    int4* p4 = reinterpret_cast<int4*>(P + (size_t)bid * SEG + t * 16);
    int4 a = p4[0], b = p4[1], c = p4[2], d = p4[3];
    int v[16] = {a.x, a.y, a.z, a.w, b.x, b.y, b.z, b.w,
                 c.x, c.y, c.z, c.w, d.x, d.y, d.z, d.w};
    int s = 0;
#pragma unroll
    for (int e = 0; e < 16; ++e) s += v[e];
    __shared__ int sc[256];
    sc[t] = s;
    __syncthreads();
#pragma unroll
    for (int off = 1; off < 256; off <<= 1) {
        int x = (t >= off) ? sc[t - off] : 0;
        __syncthreads();
        sc[t] += x;
        __syncthreads();
    }
    int incl = sc[t];
    if (t == 255) Bsums[bid] = incl;
    int run = incl - s;
#pragma unroll
    for (int e = 0; e < 16; ++e) { int x = v[e]; v[e] = run; run += x; }
    p4[0] = make_int4(v[0], v[1], v[2], v[3]);
    p4[1] = make_int4(v[4], v[5], v[6], v[7]);
    p4[2] = make_int4(v[8], v[9], v[10], v[11]);
    p4[3] = make_int4(v[12], v[13], v[14], v[15]);
}

__global__ __launch_bounds__(256) void k_scan_sums(int* __restrict__ Bsums) {
    __shared__ int sc[256];
    __shared__ int carry_s;
    int t = threadIdx.x;
    if (t == 0) carry_s = 0;
    __syncthreads();
    for (int base = 0; base < NSEG; base += 256) {
        int idx = base + t;
        int vv = (idx < NSEG) ? Bsums[idx] : 0;
        sc[t] = vv;
        __syncthreads();
#pragma unroll
        for (int off = 1; off < 256; off <<= 1) {
            int x = (t >= off) ? sc[t - off] : 0;
            __syncthreads();
            sc[t] += x;
            __syncthreads();
        }
        int incl = sc[t];
        int carry = carry_s;
        if (idx < NSEG) Bsums[idx] = carry + incl - vv;
        __syncthreads();
        if (t == 255) carry_s = carry + incl;
        __syncthreads();
    }
}

// rank every tile; record key, contributor bitmask, packed first-contributor
// descriptor (atomicMin -> lowest batch wins == numpy first segment member).
__global__ void k_slots(const int* __restrict__ loc, const int* __restrict__ P,
                        const int* __restrict__ Bsums, int* __restrict__ ukeys,
                        unsigned long long* __restrict__ mask,
                        unsigned int* __restrict__ desc) {
    int m = blockIdx.x * blockDim.x + threadIdx.x;
    if (m >= M) return;
    int b = m / CELLS, cell = m % CELLS;
    int i = cell / (NC1 * NC2), j = (cell / NC2) % NC1, k = cell % NC2;
    int l0 = loc[b * 3 + 0], l1 = loc[b * 3 + 1], l2 = loc[b * 3 + 2];
    int d = enc(l0 / 10 + i, l1 / 10 + j, l2 / 10 + k);
    int rank = P[d] + Bsums[d / SEG];
    ukeys[rank] = d;
    atomicOr(&mask[rank], 1ull << b);
    unsigned int o0 = (unsigned int)(10 * i - l0 % 10 + 9);
    unsigned int o1 = (unsigned int)(10 * j - l1 % 10 + 9);
    unsigned int o2 = (unsigned int)(10 * k - l2 % 10 + 9);
    atomicMin(&desc[rank], ((unsigned int)b << 24) | (o0 << 16) | (o1 << 8) | o2);
}

// ---- per-rank gather helpers (named-scalar state only, no arrays) ----

// z0 <= 6: the 4 elems share one source row
__device__ __forceinline__ void rank_fast(const float* __restrict__ data,
        unsigned int dsc, int x, int y, int z0,
        float& a0, float& a1, float& a2, float& a3) {
    int b  = (int)(dsc >> 24); if (b > 63) b = 0;   // invalid -> safe base
    int o0 = (int)((dsc >> 16) & 255) - 9;
    int o1 = (int)((dsc >>  8) & 255) - 9;
    int o2 = (int)(dsc & 255) - 9;
    int p0 = o0 + x, p1 = o1 + y, p2 = o2 + z0;
    if ((unsigned)p0 < (unsigned)V0d && (unsigned)p1 < (unsigned)V1d) {
        const float* s = data + (size_t)b * VOL + (p0 * V1d + p1) * V2d + p2;
        if (p2 >= 0 && p2 <= V2d - 4) {
            a0 += s[0]; a1 += s[1]; a2 += s[2]; a3 += s[3];
        } else {
            if ((unsigned)p2       < (unsigned)V2d) a0 += s[0];
            if ((unsigned)(p2 + 1) < (unsigned)V2d) a1 += s[1];
            if ((unsigned)(p2 + 2) < (unsigned)V2d) a2 += s[2];
            if ((unsigned)(p2 + 3) < (unsigned)V2d) a3 += s[3];
        }
    }
}

// z0 == 8: group straddles a y-row boundary; per-element
__device__ __forceinline__ void rank_slow(const float* __restrict__ data,
        unsigned int dsc, int e0,
        float& a0, float& a1, float& a2, float& a3) {
    int b  = (int)(dsc >> 24); if (b > 63) b = 0;
    int o0 = (int)((dsc >> 16) & 255) - 9;
    int o1 = (int)((dsc >>  8) & 255) - 9;
    int o2 = (int)(dsc & 255) - 9;
    const float* db = data + (size_t)b * VOL;
    float v0 = 0.f, v1 = 0.f, v2 = 0.f, v3 = 0.f;
#pragma unroll
    for (int j = 0; j < 4; ++j) {
        int e = e0 + j;
        int xx = e / 100, rj = e % 100;
        int yy = rj / 10, zz = rj % 10;
        int q0 = o0 + xx, q1 = o1 + yy, q2 = o2 + zz;
        if ((unsigned)q0 < (unsigned)V0d && (unsigned)q1 < (unsigned)V1d &&
            (unsigned)q2 < (unsigned)V2d) {
            float v = db[(q0 * V1d + q1) * V2d + q2];
            if (j == 0) v0 = v; else if (j == 1) v1 = v;
            else if (j == 2) v2 = v; else v3 = v;
        }
    }
    a0 += v0; a1 += v1; a2 += v2; a3 += v3;
}

// rare extra contributors (ascending b == numpy segment-sum order)
__device__ __forceinline__ void rank_extras(const float* __restrict__ data,
        const int* __restrict__ loc, unsigned long long mk, int key, int e0,
        float& a0, float& a1, float& a2, float& a3) {
    unsigned long long mke = mk & (mk - 1);   // lowest bit == desc contributor
    while (mke) {
        int b = __builtin_ctzll(mke);
        mke &= mke - 1;
        int l0 = loc[b * 3 + 0], l1 = loc[b * 3 + 1], l2 = loc[b * 3 + 2];
        int rem = key % (C1MAX * C2MAX);
        int o0 = (key / (C1MAX * C2MAX)) * 10 - l0;
        int o1 = (rem / C2MAX) * 10 - l1;
        int o2 = (rem % C2MAX) * 10 - l2;
        const float* db = data + (size_t)b * VOL;
#pragma unroll
        for (int j = 0; j < 4; ++j) {
            int e = e0 + j;
            int xx = e / 100, rj = e % 100;
            int yy = rj / 10, zz = rj % 10;
            int q0 = o0 + xx, q1 = o1 + yy, q2 = o2 + zz;
            if ((unsigned)q0 < (unsigned)V0d && (unsigned)q1 < (unsigned)V1d &&
                (unsigned)q2 < (unsigned)V2d) {
                float v = db[(q0 * V1d + q1) * V2d + q2];
                if (j == 0) a0 += v; else if (j == 1) a1 += v;
                else if (j == 2) a2 += v; else a3 += v;
            }
        }
    }
}

// 4 ranks per block: shared decode, merged scalar preamble, 4 independent
// gathers in flight per thread. No LDS, no barriers, named scalars only.
__global__ __launch_bounds__(256) void k_out(const float* __restrict__ data,
        const int* __restrict__ loc, const int* __restrict__ ukeys,
        const unsigned long long* __restrict__ mask,
        const unsigned int* __restrict__ desc,
        float* __restrict__ out, long long base_ul) {
    // bijective XCD swizzle on rank-quads: NQ = 8400 = 8 * 1050
    int orig = blockIdx.x;
    int q = (orig & 7) * (NQ / 8) + (orig >> 3);
    int r0 = q * RPB;
    int t = threadIdx.x;

    // merged per-block loads (16B aligned by construction)
    uint4      dv  = *reinterpret_cast<const uint4*>(desc + r0);
    int4       kv  = *reinterpret_cast<const int4*>(ukeys + r0);
    ulonglong2 mv0 = *reinterpret_cast<const ulonglong2*>(mask + r0);
    ulonglong2 mv1 = *reinterpret_cast<const ulonglong2*>(mask + r0 + 2);

    int e0 = t * 4;
    int x = e0 / 100, rm = e0 % 100, y = rm / 10, z0 = rm % 10;

    float aA0=0,aA1=0,aA2=0,aA3=0;
    float aB0=0,aB1=0,aB2=0,aB3=0;
    float aC0=0,aC1=0,aC2=0,aC3=0;
    float aD0=0,aD1=0,aD2=0,aD3=0;

    if (z0 <= 6) {
        rank_fast(data, dv.x, x, y, z0, aA0, aA1, aA2, aA3);
        rank_fast(data, dv.y, x, y, z0, aB0, aB1, aB2, aB3);
        rank_fast(data, dv.z, x, y, z0, aC0, aC1, aC2, aC3);
        rank_fast(data, dv.w, x, y, z0, aD0, aD1, aD2, aD3);
    } else {
        rank_slow(data, dv.x, e0, aA0, aA1, aA2, aA3);
        rank_slow(data, dv.y, e0, aB0, aB1, aB2, aB3);
        rank_slow(data, dv.z, e0, aC0, aC1, aC2, aC3);
        rank_slow(data, dv.w, e0, aD0, aD1, aD2, aD3);
    }
    // multi-contributor ranks are ~0.02% of blocks; wave-uniform guards
    if (mv0.x & (mv0.x - 1)) rank_extras(data, loc, mv0.x, kv.x, e0, aA0, aA1, aA2, aA3);
    if (mv0.y & (mv0.y - 1)) rank_extras(data, loc, mv0.y, kv.y, e0, aB0, aB1, aB2, aB3);
    if (mv1.x & (mv1.x - 1)) rank_extras(data, loc, mv1.x, kv.z, e0, aC0, aC1, aC2, aC3);
    if (mv1.y & (mv1.y - 1)) rank_extras(data, loc, mv1.y, kv.w, e0, aD0, aD1, aD2, aD3);

    if (t < 250) {
        long long ob = (long long)r0 * CHVOL + e0;
        *reinterpret_cast<float4*>(out + ob) =
            make_float4(bf16r(aA0), bf16r(aA1), bf16r(aA2), bf16r(aA3));
        *reinterpret_cast<float4*>(out + ob + CHVOL) =
            make_float4(bf16r(aB0), bf16r(aB1), bf16r(aB2), bf16r(aB3));
        *reinterpret_cast<float4*>(out + ob + 2 * CHVOL) =
            make_float4(bf16r(aC0), bf16r(aC1), bf16r(aC2), bf16r(aC3));
        *reinterpret_cast<float4*>(out + ob + 3 * CHVOL) =
            make_float4(bf16r(aD0), bf16r(aD1), bf16r(aD2), bf16r(aD3));
    }
    if (t < RPB) {  // fused uloc (output 1): lane t writes rank r0+t
        unsigned int d = (t == 0) ? dv.x : (t == 1) ? dv.y : (t == 2) ? dv.z : dv.w;
        int key       = (t == 0) ? kv.x : (t == 1) ? kv.y : (t == 2) ? kv.z : kv.w;
        float u0, u1, u2;
        if (d != 0xFFFFFFFFu) {
            int rem = key % (C1MAX * C2MAX);
            u0 = (float)((key / (C1MAX * C2MAX)) * 10);
            u1 = (float)((rem / C2MAX) * 10);
            u2 = (float)((rem % C2MAX) * 10);
        } else {  // jnp.unique fill 2^31-1 decoded: (327670, 2550, 2550)
            u0 = 327670.f; u1 = 2550.f; u2 = 2550.f;
        }
        long long i = base_ul + (long long)(r0 + t) * 3;
        out[i + 0] = bf16r(u0);
        out[i + 1] = bf16r(u1);
        out[i + 2] = bf16r(u2);
    }
}

extern "C" void kernel_launch(void* const* d_in, const int* in_sizes, int n_in,
                              void* d_out, int out_size, void* d_ws, size_t ws_size,
                              hipStream_t stream) {
    const float* data = (const float*)d_in[0];
    const int* loc    = (const int*)d_in[1];
    float* out        = (float*)d_out;

    const size_t bytesP  = (size_t)KSP * 4;                       // 5.19 MB
    const size_t bytesSm = (size_t)M * 16                         // mask+desc+ukeys
                         + (size_t)(NSEG + 64) * 4 + 64;          // Bsums+pad

    char* ws = (char*)d_ws;
    int* P;
    char* smalls;
    if (ws_size >= bytesP + bytesSm) {
        P      = (int*)ws;
        smalls = ws + bytesP;
    } else {
        // Fallback: dense array lives in the head of output 0 (dead before
        // k_out, the only later writer of that region).
        P      = (int*)d_out;
        smalls = ws;
    }
    unsigned long long* mask = (unsigned long long*)smalls;        // 16B-aligned
    unsigned int* desc = (unsigned int*)(smalls + (size_t)M * 8);  // 16B-aligned
    int* ukeys = (int*)(smalls + (size_t)M * 12);                  // 16B-aligned
    int* Bsums = (int*)(smalls + (size_t)M * 16);

    long long out_sz  = (long long)out_size;                // 33,700,800 floats
    long long base_ul = out_sz - (long long)3 * M;          // 33,600,000

    k_zero<<<640, 256, 0, stream>>>(P, (int4*)mask, (int4*)desc);
    k_mark<<<(M + 255) / 256, 256, 0, stream>>>(loc, P);
    k_scan_blocks<<<NSEG, 256, 0, stream>>>(P, Bsums);
    k_scan_sums<<<1, 256, 0, stream>>>(Bsums);
    k_slots<<<(M + 255) / 256, 256, 0, stream>>>(loc, P, Bsums, ukeys, mask, desc);
    k_out<<<NQ, 256, 0, stream>>>(data, loc, ukeys, mask, desc, out, base_ul);
}

// Round 9
// 64.693 us; speedup vs baseline: 1.1615x; 1.1615x over previous
//
#include <hip/hip_runtime.h>
#include <hip/hip_bf16.h>

namespace {
constexpr int NB    = 64;
constexpr int V0d   = 40, V1d = 40, V2d = 200;
constexpr int VOL   = V0d * V1d * V2d;        // 320,000
constexpr int NC0   = 5, NC1 = 5, NC2 = 21;
constexpr int CELLS = NC0 * NC1 * NC2;        // 525
constexpr int M     = NB * CELLS;             // 33600
constexpr int C1MAX = 104, C2MAX = 120;
constexpr int KS    = 104 * C1MAX * C2MAX;    // 1,297,920 dense compact keys
constexpr int SEG   = 4096;
constexpr int NSEG  = (KS + SEG - 1) / SEG;   // 317
constexpr int KSP   = NSEG * SEG;             // 1,298,432 (padded)
constexpr int CHVOL = 1000;
}

// Round through bf16 (expected outputs are bf16-rounded float32 values).
__device__ __forceinline__ float bf16r(float v) {
    return __bfloat162float(__float2bfloat16(v));
}

__device__ __forceinline__ int enc(int c0, int c1, int c2) {
    return (c0 * C1MAX + c1) * C2MAX + c2;
}

__global__ void k_zero(int* __restrict__ P, int4* __restrict__ mask4,
                       int4* __restrict__ desc4) {
    int idx = blockIdx.x * blockDim.x + threadIdx.x;
    int stride = gridDim.x * blockDim.x;
    int4* p4 = reinterpret_cast<int4*>(P);
    const int n4 = KSP / 4;
    for (int i = idx; i < n4; i += stride) p4[i] = make_int4(0, 0, 0, 0);
    const int m4 = M * 8 / 16;          // mask[M] (u64)
    for (int i = idx; i < m4; i += stride) mask4[i] = make_int4(0, 0, 0, 0);
    const int d4 = M * 4 / 16;          // desc[M] (u32)
    for (int i = idx; i < d4; i += stride) desc4[i] = make_int4(-1, -1, -1, -1);
}

__global__ void k_mark(const int* __restrict__ loc, int* __restrict__ P) {
    int m = blockIdx.x * blockDim.x + threadIdx.x;
    if (m >= M) return;
    int b = m / CELLS, cell = m % CELLS;
    int i = cell / (NC1 * NC2), j = (cell / NC2) % NC1, k = cell % NC2;
    P[enc(loc[b * 3 + 0] / 10 + i, loc[b * 3 + 1] / 10 + j,
          loc[b * 3 + 2] / 10 + k)] = 1;
}

__global__ __launch_bounds__(256) void k_scan_blocks(int* __restrict__ P,
                                                     int* __restrict__ Bsums) {
    int bid = blockIdx.x, t = threadIdx.x;
    int4* p4 = reinterpret_cast<int4*>(P + (size_t)bid * SEG + t * 16);
    int4 a = p4[0], b = p4[1], c = p4[2], d = p4[3];
    int v[16] = {a.x, a.y, a.z, a.w, b.x, b.y, b.z, b.w,
                 c.x, c.y, c.z, c.w, d.x, d.y, d.z, d.w};
    int s = 0;
#pragma unroll
    for (int e = 0; e < 16; ++e) s += v[e];
    __shared__ int sc[256];
    sc[t] = s;
    __syncthreads();
#pragma unroll
    for (int off = 1; off < 256; off <<= 1) {
        int x = (t >= off) ? sc[t - off] : 0;
        __syncthreads();
        sc[t] += x;
        __syncthreads();
    }
    int incl = sc[t];
    if (t == 255) Bsums[bid] = incl;
    int run = incl - s;
#pragma unroll
    for (int e = 0; e < 16; ++e) { int x = v[e]; v[e] = run; run += x; }
    p4[0] = make_int4(v[0], v[1], v[2], v[3]);
    p4[1] = make_int4(v[4], v[5], v[6], v[7]);
    p4[2] = make_int4(v[8], v[9], v[10], v[11]);
    p4[3] = make_int4(v[12], v[13], v[14], v[15]);
}

__global__ __launch_bounds__(256) void k_scan_sums(int* __restrict__ Bsums) {
    __shared__ int sc[256];
    __shared__ int carry_s;
    int t = threadIdx.x;
    if (t == 0) carry_s = 0;
    __syncthreads();
    for (int base = 0; base < NSEG; base += 256) {
        int idx = base + t;
        int vv = (idx < NSEG) ? Bsums[idx] : 0;
        sc[t] = vv;
        __syncthreads();
#pragma unroll
        for (int off = 1; off < 256; off <<= 1) {
            int x = (t >= off) ? sc[t - off] : 0;
            __syncthreads();
            sc[t] += x;
            __syncthreads();
        }
        int incl = sc[t];
        int carry = carry_s;
        if (idx < NSEG) Bsums[idx] = carry + incl - vv;
        __syncthreads();
        if (t == 255) carry_s = carry + incl;
        __syncthreads();
    }
}

// rank every tile; record key, contributor bitmask, packed first-contributor
// descriptor (atomicMin -> lowest batch wins == numpy first segment member).
__global__ void k_slots(const int* __restrict__ loc, const int* __restrict__ P,
                        const int* __restrict__ Bsums, int* __restrict__ ukeys,
                        unsigned long long* __restrict__ mask,
                        unsigned int* __restrict__ desc) {
    int m = blockIdx.x * blockDim.x + threadIdx.x;
    if (m >= M) return;
    int b = m / CELLS, cell = m % CELLS;
    int i = cell / (NC1 * NC2), j = (cell / NC2) % NC1, k = cell % NC2;
    int l0 = loc[b * 3 + 0], l1 = loc[b * 3 + 1], l2 = loc[b * 3 + 2];
    int d = enc(l0 / 10 + i, l1 / 10 + j, l2 / 10 + k);
    int rank = P[d] + Bsums[d / SEG];
    ukeys[rank] = d;
    atomicOr(&mask[rank], 1ull << b);
    unsigned int o0 = (unsigned int)(10 * i - l0 % 10 + 9);
    unsigned int o1 = (unsigned int)(10 * j - l1 % 10 + 9);
    unsigned int o2 = (unsigned int)(10 * k - l2 % 10 + 9);
    atomicMin(&desc[rank], ((unsigned int)b << 24) | (o0 << 16) | (o1 << 8) | o2);
}

// one block per output slot, block-strided element mapping: thread t handles
// e = t + 256k (k=0..3). Consecutive lanes -> consecutive z -> a wave's load
// touches ~7 source-row segments instead of ~26 (4x fewer TA line
// transactions). Stores: 4x dword, 256B contiguous per wave per instr.
__global__ __launch_bounds__(256) void k_out(const float* __restrict__ data,
        const int* __restrict__ loc, const int* __restrict__ ukeys,
        const unsigned long long* __restrict__ mask,
        const unsigned int* __restrict__ desc,
        float* __restrict__ out, long long base_ul) {
    // bijective XCD swizzle: M = 33600 = 8 * 4200
    int orig = blockIdx.x;
    int r = (orig & 7) * (M / 8) + (orig >> 3);
    int t = threadIdx.x;

    unsigned int dsc = desc[r];                  // parallel uniform loads
    unsigned long long mk = mask[r];
    int key = ukeys[r];
    bool valid = (dsc != 0xFFFFFFFFu);

    float acc[4] = {0.f, 0.f, 0.f, 0.f};

    if (valid) {
        // first contributor from the descriptor
        int b  = (int)(dsc >> 24);
        int o0 = (int)((dsc >> 16) & 255) - 9;
        int o1 = (int)((dsc >>  8) & 255) - 9;
        int o2 = (int)(dsc & 255) - 9;
        const float* db = data + (size_t)b * VOL;
#pragma unroll
        for (int k = 0; k < 4; ++k) {
            int e = t + 256 * k;
            if (e < CHVOL) {
                int x = e / 100, rm = e % 100;
                int y = rm / 10, z = rm % 10;
                int p0 = o0 + x, p1 = o1 + y, p2 = o2 + z;
                if ((unsigned)p0 < (unsigned)V0d &&
                    (unsigned)p1 < (unsigned)V1d &&
                    (unsigned)p2 < (unsigned)V2d)
                    acc[k] += db[(p0 * V1d + p1) * V2d + p2];
            }
        }
        // rare extra contributors (ascending b == numpy segment-sum order;
        // lowest bit is the desc contributor -> cleared first)
        unsigned long long mke = mk & (mk - 1);
        while (mke) {
            int b2 = __builtin_ctzll(mke);
            mke &= mke - 1;
            int l0 = loc[b2 * 3 + 0], l1 = loc[b2 * 3 + 1], l2 = loc[b2 * 3 + 2];
            int rem = key % (C1MAX * C2MAX);
            int q0 = (key / (C1MAX * C2MAX)) * 10 - l0;
            int q1 = (rem / C2MAX) * 10 - l1;
            int q2 = (rem % C2MAX) * 10 - l2;
            const float* db2 = data + (size_t)b2 * VOL;
#pragma unroll
            for (int k = 0; k < 4; ++k) {
                int e = t + 256 * k;
                if (e < CHVOL) {
                    int x = e / 100, rm = e % 100;
                    int y = rm / 10, z = rm % 10;
                    int p0 = q0 + x, p1 = q1 + y, p2 = q2 + z;
                    if ((unsigned)p0 < (unsigned)V0d &&
                        (unsigned)p1 < (unsigned)V1d &&
                        (unsigned)p2 < (unsigned)V2d)
                        acc[k] += db2[(p0 * V1d + p1) * V2d + p2];
                }
            }
        }
    }

    long long ob = (long long)r * CHVOL + t;
#pragma unroll
    for (int k = 0; k < 4; ++k) {
        int e = t + 256 * k;
        if (e < CHVOL) out[ob + 256 * k] = bf16r(acc[k]);
    }
    if (t == 0) {  // fused uloc write (output 1)
        float u0, u1, u2;
        if (valid) {
            int rem = key % (C1MAX * C2MAX);
            u0 = (float)((key / (C1MAX * C2MAX)) * 10);
            u1 = (float)((rem / C2MAX) * 10);
            u2 = (float)((rem % C2MAX) * 10);
        } else {  // jnp.unique fill 2^31-1 decoded: (327670, 2550, 2550)
            u0 = 327670.f; u1 = 2550.f; u2 = 2550.f;
        }
        long long i = base_ul + (long long)r * 3;
        out[i + 0] = bf16r(u0);
        out[i + 1] = bf16r(u1);
        out[i + 2] = bf16r(u2);
    }
}

extern "C" void kernel_launch(void* const* d_in, const int* in_sizes, int n_in,
                              void* d_out, int out_size, void* d_ws, size_t ws_size,
                              hipStream_t stream) {
    const float* data = (const float*)d_in[0];
    const int* loc    = (const int*)d_in[1];
    float* out        = (float*)d_out;

    const size_t bytesP  = (size_t)KSP * 4;                       // 5.19 MB
    const size_t bytesSm = (size_t)M * 16                         // mask+desc+ukeys
                         + (size_t)(NSEG + 64) * 4 + 64;          // Bsums+pad

    char* ws = (char*)d_ws;
    int* P;
    char* smalls;
    if (ws_size >= bytesP + bytesSm) {
        P      = (int*)ws;
        smalls = ws + bytesP;
    } else {
        // Fallback: dense array lives in the head of output 0 (dead before
        // k_out, the only later writer of that region).
        P      = (int*)d_out;
        smalls = ws;
    }
    unsigned long long* mask = (unsigned long long*)smalls;        // 16B-aligned
    unsigned int* desc = (unsigned int*)(smalls + (size_t)M * 8);  // 16B-aligned
    int* ukeys = (int*)(smalls + (size_t)M * 12);                  // 16B-aligned
    int* Bsums = (int*)(smalls + (size_t)M * 16);

    long long out_sz  = (long long)out_size;                // 33,700,800 floats
    long long base_ul = out_sz - (long long)3 * M;          // 33,600,000

    k_zero<<<640, 256, 0, stream>>>(P, (int4*)mask, (int4*)desc);
    k_mark<<<(M + 255) / 256, 256, 0, stream>>>(loc, P);
    k_scan_blocks<<<NSEG, 256, 0, stream>>>(P, Bsums);
    k_scan_sums<<<1, 256, 0, stream>>>(Bsums);
    k_slots<<<(M + 255) / 256, 256, 0, stream>>>(loc, P, Bsums, ukeys, mask, desc);
    k_out<<<M, 256, 0, stream>>>(data, loc, ukeys, mask, desc, out, base_ul);
}

// Round 10
// 60.853 us; speedup vs baseline: 1.2347x; 1.0631x over previous
//
#include <hip/hip_runtime.h>
#include <hip/hip_bf16.h>

namespace {
constexpr int NB    = 64;
constexpr int V0d   = 40, V1d = 40, V2d = 200;
constexpr int VOL   = V0d * V1d * V2d;        // 320,000
constexpr int NC0   = 5, NC1 = 5, NC2 = 21;
constexpr int CELLS = NC0 * NC1 * NC2;        // 525
constexpr int M     = NB * CELLS;             // 33600
constexpr int C1MAX = 104, C2MAX = 120;
constexpr int KS    = 104 * C1MAX * C2MAX;    // 1,297,920 dense compact keys
constexpr int NWORDS = KS / 32;               // 40,560 bitmask words
constexpr int NSB    = (NWORDS + 255) / 256;  // 159 scan blocks
constexpr int NWPAD  = NSB * 256;             // 40,704 (WP padded)
constexpr int CHVOL  = 1000;
}

typedef float f32x4 __attribute__((ext_vector_type(4)));

// Round through bf16 (expected outputs are bf16-rounded float32 values).
__device__ __forceinline__ float bf16r(float v) {
    return __bfloat162float(__float2bfloat16(v));
}

__device__ __forceinline__ int enc(int c0, int c1, int c2) {
    return (c0 * C1MAX + c1) * C2MAX + c2;
}

// zero bitmask W (162 KB) + contributor masks (269 KB) — tiny now
__global__ void k_zero(int4* __restrict__ W4, int4* __restrict__ mask4) {
    int idx = blockIdx.x * blockDim.x + threadIdx.x;
    int stride = gridDim.x * blockDim.x;
    const int w4 = NWORDS / 4;          // 10,140
    for (int i = idx; i < w4; i += stride) W4[i] = make_int4(0, 0, 0, 0);
    const int m4 = M * 8 / 16;          // 16,800
    for (int i = idx; i < m4; i += stride) mask4[i] = make_int4(0, 0, 0, 0);
}

__global__ void k_mark(const int* __restrict__ loc, unsigned* __restrict__ W) {
    int m = blockIdx.x * blockDim.x + threadIdx.x;
    if (m >= M) return;
    int b = m / CELLS, cell = m % CELLS;
    int i = cell / (NC1 * NC2), j = (cell / NC2) % NC1, k = cell % NC2;
    int d = enc(loc[b * 3 + 0] / 10 + i, loc[b * 3 + 1] / 10 + j,
                loc[b * 3 + 2] / 10 + k);
    atomicOr(&W[d >> 5], 1u << (d & 31));
}

// per-word exclusive popcount prefix within each 256-word block
__global__ __launch_bounds__(256) void k_scan_words(const unsigned* __restrict__ W,
                                                    unsigned* __restrict__ WP,
                                                    int* __restrict__ Bsums) {
    int t = threadIdx.x;
    int w = blockIdx.x * 256 + t;
    int c = (w < NWORDS) ? __popc(W[w]) : 0;
    __shared__ int sc[256];
    sc[t] = c;
    __syncthreads();
#pragma unroll
    for (int off = 1; off < 256; off <<= 1) {
        int x = (t >= off) ? sc[t - off] : 0;
        __syncthreads();
        sc[t] += x;
        __syncthreads();
    }
    int incl = sc[t];
    WP[w] = (unsigned)(incl - c);       // WP padded to NWPAD
    if (t == 255) Bsums[blockIdx.x] = incl;
}

// exclusive scan of the 159 block sums (single pass, NSB < 256)
__global__ __launch_bounds__(256) void k_scan_sums(int* __restrict__ Bsums) {
    int t = threadIdx.x;
    int vv = (t < NSB) ? Bsums[t] : 0;
    __shared__ int sc[256];
    sc[t] = vv;
    __syncthreads();
#pragma unroll
    for (int off = 1; off < 256; off <<= 1) {
        int x = (t >= off) ? sc[t - off] : 0;
        __syncthreads();
        sc[t] += x;
        __syncthreads();
    }
    if (t < NSB) Bsums[t] = sc[t] - vv;
}

// rank every tile: rank = blockOff + wordPrefix + popcount(bits below);
// record unique key + contributor bitmask per rank.
__global__ void k_slots(const int* __restrict__ loc, const unsigned* __restrict__ W,
                        const unsigned* __restrict__ WP, const int* __restrict__ Bsums,
                        int* __restrict__ ukeys, unsigned long long* __restrict__ mask) {
    int m = blockIdx.x * blockDim.x + threadIdx.x;
    if (m >= M) return;
    int b = m / CELLS, cell = m % CELLS;
    int i = cell / (NC1 * NC2), j = (cell / NC2) % NC1, k = cell % NC2;
    int d = enc(loc[b * 3 + 0] / 10 + i, loc[b * 3 + 1] / 10 + j,
                loc[b * 3 + 2] / 10 + k);
    int w = d >> 5, bp = d & 31;
    unsigned wd = W[w];
    int rank = Bsums[w >> 8] + (int)WP[w] + __popc(wd & ((1u << bp) - 1u));
    ukeys[rank] = d;                     // same value from all writers
    atomicOr(&mask[rank], 1ull << b);    // order-independent -> deterministic
}

// one block per output slot; R5-proven gather structure + non-temporal
// stores (keep input L3-resident across graph replays).
__global__ __launch_bounds__(256) void k_out(const float* __restrict__ data,
        const int* __restrict__ loc, const int* __restrict__ ukeys,
        const unsigned long long* __restrict__ mask,
        float* __restrict__ out, long long base_ul) {
    // bijective XCD swizzle: M = 33600 = 8 * 4200
    int orig = blockIdx.x;
    int r = (orig & 7) * (M / 8) + (orig >> 3);
    int t = threadIdx.x;

    unsigned long long mk = mask[r];     // uniform -> s_load
    int key = ukeys[r];                  // uniform -> s_load (garbage if !valid)
    bool valid = (mk != 0ull);

    float ax = 0.f, ay = 0.f, az = 0.f, aw = 0.f;
    int c0 = 0, c1 = 0, c2 = 0;
    if (valid) {
        c0 = key / (C1MAX * C2MAX);
        int rem = key % (C1MAX * C2MAX);
        c1 = rem / C2MAX;
        c2 = rem % C2MAX;
        if (t < 250) {
            int e0 = t * 4;
            int x  = e0 / 100;
            int rm = e0 % 100;
            int y  = rm / 10;
            int z0 = rm % 10;            // in {0,2,4,6,8}
            int g0 = c0 * 10, g1 = c1 * 10, g2 = c2 * 10;
            unsigned long long m2 = mk;
            while (m2) {                 // ascending b == numpy order
                int b = __builtin_ctzll(m2);
                m2 &= m2 - 1;
                int l0 = loc[b * 3 + 0], l1 = loc[b * 3 + 1], l2 = loc[b * 3 + 2];
                const float* db = data + (size_t)b * VOL;
                if (z0 <= 6) {
                    // all 4 elems share one source row (x,y)
                    int p0 = g0 - l0 + x, p1 = g1 - l1 + y, p2 = g2 - l2 + z0;
                    if ((unsigned)p0 < (unsigned)V0d &&
                        (unsigned)p1 < (unsigned)V1d) {
                        const float* s = db + (p0 * V1d + p1) * V2d + p2;
                        if (p2 >= 0 && p2 <= V2d - 4) {
                            ax += s[0]; ay += s[1]; az += s[2]; aw += s[3];
                        } else {
                            if ((unsigned)p2       < (unsigned)V2d) ax += s[0];
                            if ((unsigned)(p2 + 1) < (unsigned)V2d) ay += s[1];
                            if ((unsigned)(p2 + 2) < (unsigned)V2d) az += s[2];
                            if ((unsigned)(p2 + 3) < (unsigned)V2d) aw += s[3];
                        }
                    }
                } else {
                    // z0 == 8: group straddles a y-row boundary; per-element
                    float av[4] = {0.f, 0.f, 0.f, 0.f};
#pragma unroll
                    for (int jj = 0; jj < 4; ++jj) {
                        int e  = e0 + jj;
                        int xx = e / 100;
                        int rj = e % 100;
                        int yy = rj / 10, zz = rj % 10;
                        int q0 = g0 - l0 + xx, q1 = g1 - l1 + yy,
                            q2 = g2 - l2 + zz;
                        if ((unsigned)q0 < (unsigned)V0d &&
                            (unsigned)q1 < (unsigned)V1d &&
                            (unsigned)q2 < (unsigned)V2d)
                            av[jj] = db[(q0 * V1d + q1) * V2d + q2];
                    }
                    ax += av[0]; ay += av[1]; az += av[2]; aw += av[3];
                }
            }
        }
    }

    if (t < 250) {
        f32x4 v = {bf16r(ax), bf16r(ay), bf16r(az), bf16r(aw)};
        __builtin_nontemporal_store(v,
            reinterpret_cast<f32x4*>(out + (long long)r * CHVOL + t * 4));
    }
    if (t == 0) {  // fused uloc write (output 1)
        float u0, u1, u2;
        if (valid) {
            u0 = (float)(c0 * 10);
            u1 = (float)(c1 * 10);
            u2 = (float)(c2 * 10);
        } else {  // jnp.unique fill 2^31-1 decoded: (327670, 2550, 2550)
            u0 = 327670.f; u1 = 2550.f; u2 = 2550.f;
        }
        long long i = base_ul + (long long)r * 3;
        __builtin_nontemporal_store(bf16r(u0), out + i + 0);
        __builtin_nontemporal_store(bf16r(u1), out + i + 1);
        __builtin_nontemporal_store(bf16r(u2), out + i + 2);
    }
}

extern "C" void kernel_launch(void* const* d_in, const int* in_sizes, int n_in,
                              void* d_out, int out_size, void* d_ws, size_t ws_size,
                              hipStream_t stream) {
    const float* data = (const float*)d_in[0];
    const int* loc    = (const int*)d_in[1];
    float* out        = (float*)d_out;

    // ws layout (all 16B aligned): mask | ukeys | W | WP | Bsums   ~732 KB
    const size_t offMask  = 0;
    const size_t offKeys  = offMask + (size_t)M * 8;          // 268,800
    const size_t offW     = offKeys + (size_t)M * 4;          // 403,200
    const size_t offWP    = offW + (size_t)NWPAD * 4;         // +162,816 -> 566,016
    const size_t offBs    = offWP + (size_t)NWPAD * 4;        // 728,832
    const size_t bytesAll = offBs + (size_t)(NSB + 64) * 4;   // ~729.7 KB

    char* basep = (ws_size >= bytesAll) ? (char*)d_ws : (char*)d_out;
    // (fallback: d_out head is dead until k_out, the only later writer)

    unsigned long long* mask = (unsigned long long*)(basep + offMask);
    int*      ukeys = (int*)(basep + offKeys);
    unsigned* W     = (unsigned*)(basep + offW);
    unsigned* WP    = (unsigned*)(basep + offWP);
    int*      Bsums = (int*)(basep + offBs);

    long long out_sz  = (long long)out_size;                // 33,700,800 floats
    long long base_ul = out_sz - (long long)3 * M;          // 33,600,000

    k_zero<<<128, 256, 0, stream>>>((int4*)W, (int4*)mask);
    k_mark<<<(M + 255) / 256, 256, 0, stream>>>(loc, W);
    k_scan_words<<<NSB, 256, 0, stream>>>(W, WP, Bsums);
    k_scan_sums<<<1, 256, 0, stream>>>(Bsums);
    k_slots<<<(M + 255) / 256, 256, 0, stream>>>(loc, W, WP, Bsums, ukeys, mask);
    k_out<<<M, 256, 0, stream>>>(data, loc, ukeys, mask, out, base_ul);
}